// Round 9
// baseline (130.052 us; speedup 1.0000x reference)
//
#include <hip/hip_runtime.h>
#include <hip/hip_fp16.h>

#define NQ   12
#define DIM  4096      // 2^NQ
#define NL   2
#define BATCH 4096
#define SPB  4         // samples per qc_sim block (grid 1024 -> 3-4 blocks/CU usable)

typedef _Float16 half8  __attribute__((ext_vector_type(8)));
typedef float    f32x16 __attribute__((ext_vector_type(16)));
typedef __fp16   hv2    __attribute__((ext_vector_type(2)));

// ---------------------------------------------------------------------------
// Round-9: OCCUPANCY VIA VGPR CUT.  R8 audit: qc_sim ~37us vs ~22us HBM
// floor, pipes only ~6us busy -> latency-bound at 8 waves/CU (VGPR-capped:
// ~200/thread incl. 96 stationary). Changes:
//  * GEMM2 fragment sharing: m1f=[Br|-Bi], m2f=[Bi|Br] duplicate every
//    value. Keep Brf+Bif only (32 VGPR, was 64); per-use negation of Bi via
//    sign-bit XOR (exact in fp16): Yr = Br.Tr - Bi.Ti, Yi = Bi.Tr + Br.Ti.
//    MFMA k-blocks are independent rank-16 updates -> fragment re-indexing
//    across the k-sweep is legal. ws shrinks 48->32 KB.
//  * __launch_bounds__(256,3): VGPR cap 170 -> 12 waves/CU (+50% TLP).
//  * SPB 8->4 (grid 1024): grid 512 could never fill a 3rd block slot/CU
//    (512 < 3*256); 1024 can, still 4x fragment amortization.
// Everything else identical to R8 (verified absmax 3.05e-5):
// Y = B X A^T; GEMM1 (X real): T = X*[Ar|Ai]^T; Tc=[Tr;Ti];
// fragment maps HW-verified: A-op row=lane&31, B-op col=lane&31, k-slot
// kappa(hi,j)=hi*8+j both operands; C/D col=lane&31,
// row=(reg&3)+8*(reg>>2)+4*(lane>>5). LDS Xh 8KB + Tc 16KB, XOR-swizzled.
// ---------------------------------------------------------------------------

union U4H8 { uint4 u; half8 h; };

__device__ __forceinline__ unsigned pkrtz(float a, float b) {
    union { hv2 h; unsigned u; } c;
    c.h = __builtin_amdgcn_cvt_pkrtz(a, b);
    return c.u;
}

__global__ void build_gates(const float* __restrict__ th,
                            const float* __restrict__ ph,
                            const float* __restrict__ lm,
                            unsigned short* __restrict__ ws) {
    __shared__ float g[12][8];   // per-qubit fused gate: 00r,00i,01r,01i,10r,...
    int t = threadIdx.x;
    if (t < NQ) {
        int q = t;
        float g00r = 1.f, g00i = 0.f, g01r = 0.f, g01i = 0.f;
        float g10r = 0.f, g10i = 0.f, g11r = 1.f, g11i = 0.f;
        #pragma unroll
        for (int l = 0; l < NL; ++l) {
            float th2 = 0.5f * th[l * NQ + q];
            float p   = ph[l * NQ + q];
            float la  = lm[l * NQ + q];
            float s, c, sl, cl, sp, cp, spl, cpl;
            sincosf(th2, &s, &c);
            sincosf(la, &sl, &cl);
            sincosf(p, &sp, &cp);
            sincosf(p + la, &spl, &cpl);
            float u00r = c,        u00i = 0.f;
            float u01r = -cl * s,  u01i = -sl * s;
            float u10r = cp * s,   u10i = sp * s;
            float u11r = cpl * c,  u11i = spl * c;
            float n00r = u00r*g00r - u00i*g00i + u01r*g10r - u01i*g10i;
            float n00i = u00r*g00i + u00i*g00r + u01r*g10i + u01i*g10r;
            float n01r = u00r*g01r - u00i*g01i + u01r*g11r - u01i*g11i;
            float n01i = u00r*g01i + u00i*g01r + u01r*g11i + u01i*g11r;
            float n10r = u10r*g00r - u10i*g00i + u11r*g10r - u11i*g10i;
            float n10i = u10r*g00i + u10i*g00r + u11r*g10i + u11i*g10r;
            float n11r = u10r*g01r - u10i*g01i + u11r*g11r - u11i*g11i;
            float n11i = u10r*g01i + u10i*g01r + u11r*g11i + u11i*g11r;
            g00r = n00r; g00i = n00i; g01r = n01r; g01i = n01i;
            g10r = n10r; g10i = n10i; g11r = n11r; g11i = n11i;
        }
        g[q][0] = g00r; g[q][1] = g00i; g[q][2] = g01r; g[q][3] = g01i;
        g[q][4] = g10r; g[q][5] = g10i; g[q][6] = g11r; g[q][7] = g11i;
    }
    __syncthreads();

    // One element per thread (64 blocks x 256 = 16384):
    //  [0,8192)      arr0 (G1B, GEMM1 B-op): frag = n4*4+ks; nn=n4*32+(lane&31),
    //                k=ks*16+(lane>>5)*8+j; val = nn<64 ? ReA[nn][k] : ImA[nn-64][k]
    //  [8192,12288)  arr1 (Brf): frag = m*4+ks; r=m*32+(lane&31), k<64; val=ReB[r][k]
    //  [12288,16384) arr2 (Bif): val=ImB[r][k]   (negation applied at use site)
    {
        int idx  = blockIdx.x * 256 + t;
        int arr  = (idx < 8192) ? 0 : (idx < 12288 ? 1 : 2);
        int rem  = idx - (arr == 0 ? 0 : (arr == 1 ? 8192 : 12288));
        int frag = rem >> 9;
        int lane = (rem >> 3) & 63;
        int j    = rem & 7;
        int row, col, base, k, nn = 0;
        if (arr == 0) {
            int n4 = frag >> 2, ks = frag & 3;
            nn  = n4 * 32 + (lane & 31);
            k   = ks * 16 + ((lane >> 5) << 3) + j;   // c'
            row = nn & 63; col = k; base = 6;          // A = kron(G6..G11)
        } else {
            int m = frag >> 2, ks = frag & 3;
            row = m * 32 + (lane & 31);                // r
            k   = ks * 16 + ((lane >> 5) << 3) + j;    // k < 64
            col = k; base = 0;                         // B = kron(G0..G5)
        }
        float re = 1.f, im = 0.f;
        #pragma unroll
        for (int qq = 0; qq < 6; ++qq) {
            const float* G = g[base + qq];
            int rb = (row >> (5 - qq)) & 1;
            int cb = (col >> (5 - qq)) & 1;
            float fr = G[rb * 4 + cb * 2], fi = G[rb * 4 + cb * 2 + 1];
            float nre = re * fr - im * fi;
            float nim = re * fi + im * fr;
            re = nre; im = nim;
        }
        float val;
        if (arr == 0)      val = (nn < 64) ? re : im;
        else if (arr == 1) val = re;
        else               val = im;
        union { __fp16 h; unsigned short s; } cv;
        cv.h = (__fp16)val;
        ws[idx] = cv.s;
    }
}

__global__ __launch_bounds__(256, 3)
void qc_sim(const float* __restrict__ in,
            const unsigned short* __restrict__ gw,
            float* __restrict__ out) {
    __shared__ unsigned Xh32[2048];   // 8 KB: X fp16, row-major, granule-swz
    __shared__ unsigned Tc32[4096];   // 16 KB: Tc fp16, col-major, granule-swz
    __shared__ float red[4];

    const int t = threadIdx.x, lane = t & 63, w = t >> 6, b = blockIdx.x;
    const int m1 = w & 1, ng = (w >> 1) * 2;   // GEMM1: m-tile, n-tiles ng,ng+1
    const int m2 = w & 1, n2 = w >> 1;         // GEMM2: (m,n) quarter of Y

    // ---- stationary fragment loads, ONCE per block (uint4 0/1024/1536) ----
    const uint4* __restrict__ wsv = reinterpret_cast<const uint4*>(gw);
    uint4 g1b[2][4], brf[4], bif[4];
    #pragma unroll
    for (int n = 0; n < 2; ++n)
        #pragma unroll
        for (int ks = 0; ks < 4; ++ks)
            g1b[n][ks] = wsv[((ng + n) * 4 + ks) * 64 + lane];
    #pragma unroll
    for (int ks = 0; ks < 4; ++ks) brf[ks] = wsv[1024 + (m2 * 4 + ks) * 64 + lane];
    #pragma unroll
    for (int ks = 0; ks < 4; ++ks) bif[ks] = wsv[1536 + (m2 * 4 + ks) * 64 + lane];

    const float* __restrict__ base_in  = in  + (size_t)b * SPB * DIM;
    float*       __restrict__ base_out = out + (size_t)b * SPB * DIM;

    // ---- load first sample (coalesced float4) ----
    float4 cur[4], nxt[4];
    {
        const float4* __restrict__ x4 = reinterpret_cast<const float4*>(base_in);
        #pragma unroll
        for (int j = 0; j < 4; ++j) cur[j] = x4[j * 256 + t];
    }

    for (int s = 0; s < SPB; ++s) {
        // ---- sumsq (f32, exact) ----
        float ss = 0.f;
        #pragma unroll
        for (int j = 0; j < 4; ++j)
            ss += cur[j].x*cur[j].x + cur[j].y*cur[j].y
                + cur[j].z*cur[j].z + cur[j].w*cur[j].w;
        #pragma unroll
        for (int off = 32; off > 0; off >>= 1) ss += __shfl_down(ss, off, 64);
        if (lane == 0) red[w] = ss;

        // ---- stage X -> LDS fp16 (swizzled), then prefetch next sample ----
        #pragma unroll
        for (int j = 0; j < 4; ++j) {
            int fi = (j * 256 + t) * 4, r = fi >> 6, c = fi & 63;
            int a32 = r * 32 + ((((c >> 3) ^ (r & 7)) << 2)) + ((c & 7) >> 1);
            Xh32[a32]     = pkrtz(cur[j].x, cur[j].y);
            Xh32[a32 + 1] = pkrtz(cur[j].z, cur[j].w);
        }
        if (s + 1 < SPB) {
            const float4* __restrict__ xn =
                reinterpret_cast<const float4*>(base_in + (size_t)(s + 1) * DIM);
            #pragma unroll
            for (int j = 0; j < 4; ++j) nxt[j] = xn[j * 256 + t];
        }
        __syncthreads();   // barrier1: X + red visible
        const float inv = 1.0f / (red[0] + red[1] + red[2] + red[3]);

        // ---- GEMM1: T_ext = X * [Ar|Ai]^T (wave: m1, n-tiles ng,ng+1) ----
        f32x16 acc0 = {0,0,0,0,0,0,0,0,0,0,0,0,0,0,0,0};
        f32x16 acc1 = {0,0,0,0,0,0,0,0,0,0,0,0,0,0,0,0};
        const int rowX = m1 * 32 + (lane & 31);
        #pragma unroll
        for (int ks = 0; ks < 4; ++ks) {
            int kb  = ks * 16 + ((lane >> 5) << 3);
            int a32 = rowX * 32 + ((((kb >> 3) ^ (rowX & 7)) << 2));
            U4H8 xf; xf.u = *reinterpret_cast<const uint4*>(&Xh32[a32]);
            U4H8 b0; b0.u = g1b[0][ks];
            U4H8 b1; b1.u = g1b[1][ks];
            acc0 = __builtin_amdgcn_mfma_f32_32x32x16_f16(xf.h, b0.h, acc0, 0, 0, 0);
            acc1 = __builtin_amdgcn_mfma_f32_32x32x16_f16(xf.h, b1.h, acc1, 0, 0, 0);
        }

        // ---- write Tc = [Tr;Ti] (128x64, col-major, swizzled) ----
        #pragma unroll
        for (int tile = 0; tile < 2; ++tile) {
            int nt = ng + tile;
            const f32x16& acc = tile ? acc1 : acc0;
            int kofs = m1 * 32 + 64 * (nt >> 1) + ((lane >> 5) << 2);
            int cc   = (nt & 1) * 32 + (lane & 31);
            #pragma unroll
            for (int p = 0; p < 4; ++p) {
                int k0  = kofs + p * 8;
                int a32 = cc * 64 + (((k0 >> 3) ^ (cc & 15)) << 2) + ((k0 & 7) >> 1);
                Tc32[a32]     = pkrtz(acc[4 * p],     acc[4 * p + 1]);
                Tc32[a32 + 1] = pkrtz(acc[4 * p + 2], acc[4 * p + 3]);
            }
        }
        __syncthreads();   // barrier2: Tc visible

        // ---- GEMM2: Yr = Br.Tr - Bi.Ti, Yi = Bi.Tr + Br.Ti (quarter m2,n2)
        f32x16 accR = {0,0,0,0,0,0,0,0,0,0,0,0,0,0,0,0};
        f32x16 accI = {0,0,0,0,0,0,0,0,0,0,0,0,0,0,0,0};
        const int cT = n2 * 32 + (lane & 31);
        #pragma unroll
        for (int ks = 0; ks < 4; ++ks) {       // Tr half (k-blocks 0..3)
            int kb  = ks * 16 + ((lane >> 5) << 3);
            int a32 = cT * 64 + (((kb >> 3) ^ (cT & 15)) << 2);
            U4H8 tr; tr.u = *reinterpret_cast<const uint4*>(&Tc32[a32]);
            U4H8 br; br.u = brf[ks];
            U4H8 bi; bi.u = bif[ks];
            accR = __builtin_amdgcn_mfma_f32_32x32x16_f16(br.h, tr.h, accR, 0, 0, 0);
            accI = __builtin_amdgcn_mfma_f32_32x32x16_f16(bi.h, tr.h, accI, 0, 0, 0);
        }
        #pragma unroll
        for (int ks = 4; ks < 8; ++ks) {       // Ti half (k-blocks 4..7)
            int kb  = ks * 16 + ((lane >> 5) << 3);
            int a32 = cT * 64 + (((kb >> 3) ^ (cT & 15)) << 2);
            U4H8 ti; ti.u = *reinterpret_cast<const uint4*>(&Tc32[a32]);
            U4H8 br; br.u = brf[ks - 4];
            uint4 nb = bif[ks - 4];            // -Bi: fp16 sign-bit flip (exact)
            nb.x ^= 0x80008000u; nb.y ^= 0x80008000u;
            nb.z ^= 0x80008000u; nb.w ^= 0x80008000u;
            U4H8 nbi; nbi.u = nb;
            accR = __builtin_amdgcn_mfma_f32_32x32x16_f16(nbi.h, ti.h, accR, 0, 0, 0);
            accI = __builtin_amdgcn_mfma_f32_32x32x16_f16(br.h,  ti.h, accI, 0, 0, 0);
        }

        // ---- epilogue: prob = (Yr^2+Yi^2)*inv; C/D row=(r&3)+8*(r>>2)+4*hi
        float* __restrict__ o = base_out + (size_t)s * DIM
            + (size_t)((m2 * 32 + ((lane >> 5) << 2)) * 64 + n2 * 32 + (lane & 31));
        #pragma unroll
        for (int r = 0; r < 16; ++r) {
            int off = ((r & 3) + 8 * (r >> 2)) * 64;
            o[off] = (accR[r] * accR[r] + accI[r] * accI[r]) * inv;
        }

        // ---- rotate prefetched sample into place ----
        if (s + 1 < SPB) {
            #pragma unroll
            for (int j = 0; j < 4; ++j) cur[j] = nxt[j];
        }
    }
}

extern "C" void kernel_launch(void* const* d_in, const int* in_sizes, int n_in,
                              void* d_out, int out_size, void* d_ws, size_t ws_size,
                              hipStream_t stream) {
    (void)in_sizes; (void)n_in; (void)out_size; (void)ws_size;
    const float* inputs = (const float*)d_in[0];
    const float* thetas = (const float*)d_in[1];
    const float* phis   = (const float*)d_in[2];
    const float* lams   = (const float*)d_in[3];
    unsigned short* gates = (unsigned short*)d_ws;   // 32 KB fragment-packed
    float* out = (float*)d_out;

    hipLaunchKernelGGL(build_gates, dim3(64), dim3(256), 0, stream,
                       thetas, phis, lams, gates);
    hipLaunchKernelGGL(qc_sim, dim3(BATCH / SPB), dim3(256), 0, stream,
                       inputs, gates, out);
}